// Round 4
// baseline (233.357 us; speedup 1.0000x reference)
//
#include <hip/hip_runtime.h>
#include <hip/hip_bf16.h>
#include <math.h>

#define NPTS 20000
#define KNB  32
#define DDIM 64
#define HIDN 64
#define OUTC 192
#define PPB  4

// d_ws layout, ushort units (bf16 MFMA fragments, 512 ushorts = 1 frag)
#define WS_W2 0        // 8 frags  (ct*2+ks)
#define WS_W3 4096     // 8 frags
#define WS_W1 8192     // 4 frags  (ct)
#define WS_WG 10240    // 24 frags (ot*2+ks)
#define WS_WV 22528    // 24 frags (ot*2+ks)
// total 69632 bytes

typedef short bf16x8 __attribute__((ext_vector_type(8)));
typedef float f32x4  __attribute__((ext_vector_type(4)));

union BF8 { bf16x8 v; unsigned short us[8]; unsigned u[4]; };

__device__ __forceinline__ unsigned short f2bf(float f) {
  return __builtin_bit_cast(unsigned short, __float2bfloat16(f));
}

__device__ __forceinline__ float fast_atan2pi(float y, float x) {
  // y >= 0; returns atan2(y,x)/pi; abs err ~1e-6 (minimax deg-11 + v_rcp)
  const float ax = fabsf(x);
  const float mx = fmaxf(fmaxf(ax, y), 1e-30f);
  const float mn = fminf(ax, y);
  const float t  = mn * __builtin_amdgcn_rcpf(mx);
  const float s  = t * t;
  float p = -0.0117212f;
  p = fmaf(p, s,  0.05265332f);
  p = fmaf(p, s, -0.11643287f);
  p = fmaf(p, s,  0.19354346f);
  p = fmaf(p, s, -0.33262347f);
  p = fmaf(p, s,  0.99997726f);
  float r = p * t;
  if (y > ax)  r = 1.5707963268f - r;
  if (x < 0.f) r = 3.1415926536f - r;
  return r * 0.3183098862f;
}

__device__ __forceinline__ float angle3f(float ax, float ay, float az,
                                         float bx, float by, float bz) {
  const float y  = ax*bx + ay*by + az*bz;
  const float cx = ay*bz - az*by;
  const float cy = az*bx - ax*bz;
  const float cz = ax*by - ay*bx;
  const float xn = __builtin_amdgcn_sqrtf(cx*cx + cy*cy + cz*cz);
  return fast_atan2pi(xn, y);
}

// ---- prep: convert weights to bf16 fragment layout in d_ws ------------------
// frag element j of lane L = M[(L&15)+16*ct][(L>>4)*8 + j + 32*ks]
__global__ void prep_weights(const float* __restrict__ W1, const float* __restrict__ W2,
                             const float* __restrict__ W3, const float* __restrict__ Wg,
                             const float* __restrict__ Wv, unsigned short* __restrict__ ws)
{
  const int f  = blockIdx.x;     // 68 frags
  const int L  = threadIdx.x;    // 64 lanes
  const int ln = L & 15, lq = L >> 4;
  unsigned short vals[8];
  if (f >= 16 && f < 20) {       // W1 [64][4], K padded to 32
    const int ct = f - 16;
#pragma unroll
    for (int j = 0; j < 8; ++j) {
      const float v = (lq == 0 && j < 4) ? W1[(ln + 16*ct)*4 + j] : 0.f;
      vals[j] = f2bf(v);
    }
  } else {
    const float* M; int q;
    if (f < 8)       { M = W2; q = f; }
    else if (f < 16) { M = W3; q = f - 8; }
    else if (f < 44) { M = Wg; q = f - 20; }
    else             { M = Wv; q = f - 44; }
    const int ct = q >> 1, ks = q & 1;
    const float* src = M + (ln + 16*ct)*64 + lq*8 + 32*ks;
#pragma unroll
    for (int j = 0; j < 8; ++j) vals[j] = f2bf(src[j]);
  }
  uint4 w;
  w.x = vals[0] | ((unsigned)vals[1] << 16);
  w.y = vals[2] | ((unsigned)vals[3] << 16);
  w.z = vals[4] | ((unsigned)vals[5] << 16);
  w.w = vals[6] | ((unsigned)vals[7] << 16);
  *(uint4*)&ws[f*512 + L*8] = w;
}

// ---- gather pipeline helpers ------------------------------------------------
__device__ __forceinline__ void gather_issue(const float* __restrict__ s_feats,
                                             const int* __restrict__ nbr,
                                             int pu, int base, int lofs,
                                             float3* __restrict__ buf) {
#pragma unroll
  for (int k = 0; k < 8; ++k) {
    const int mi = nbr[pu*KNB + base + k];            // wave-uniform -> s_load
    const float* fr = s_feats + (size_t)mi*(DDIM*3) + lofs;
    buf[k] = make_float3(fr[0], fr[1], fr[2]);        // global_load_dwordx3
  }
}
__device__ __forceinline__ void gather_acc(const float3* __restrict__ buf,
                                           float& s0, float& s1, float& s2) {
#pragma unroll
  for (int k = 0; k < 8; ++k) { s0 += buf[k].x; s1 += buf[k].y; s2 += buf[k].z; }
}

// ---- main fused kernel ------------------------------------------------------
__global__ __launch_bounds__(256, 5)
void ppf_fused(const float* __restrict__ q_pts,
               const float* __restrict__ s_pts,
               const float* __restrict__ s_feats,
               const int*   __restrict__ nbr,
               const float* __restrict__ normals,
               const float* __restrict__ b1, const float* __restrict__ b2,
               const float* __restrict__ b3, const float* __restrict__ bg,
               const unsigned short* __restrict__ wsu,
               float* __restrict__ out)
{
  // s_h rows: cols 0..63 = h tile (bf16); cols 64..71 = this row's ppf float4.
  __shared__ __align__(16) unsigned short s_h[PPB][KNB][72];   // 18432 B (alias s_out)
  __shared__ __align__(16) unsigned short s_modb[16][72];      //  2304 B rows=points(pad)
  __shared__ __align__(16) unsigned short s_aggb[16][72];      //  2304 B rows=(g,t)(pad)
  __shared__ float s_gate[PPB][200];                           //  3200 B (padded)
  float* s_out = (float*)&s_h[0][0][0];                        // 4 x 592 floats

  const int tid  = threadIdx.x;
  const int g    = tid >> 6;
  const int lane = tid & 63;
  const int lq   = lane >> 4;
  const int ln   = lane & 15;
  const int pu   = __builtin_amdgcn_readfirstlane(blockIdx.x * PPB + g);
  const int lofs = lane * 3;

  float3 bufA[8], bufB[8];
  float s0 = 0.f, s1 = 0.f, s2 = 0.f;

  // chunk 0 in flight across phase A + layer 1
  gather_issue(s_feats, nbr, pu, 0, lofs, bufA);

  // ---- Phase A: PPF features, split across wave halves ----------------------
  {
    const float qx = q_pts[pu*3+0], qy = q_pts[pu*3+1], qz = q_pts[pu*3+2];
    const int   i0 = nbr[pu*KNB];
    const float qnx = normals[i0*3+0], qny = normals[i0*3+1], qnz = normals[i0*3+2];
    const int k  = lane & 31;
    const int mi = nbr[pu*KNB + k];
    const float px = s_pts[mi*3+0], py = s_pts[mi*3+1], pz = s_pts[mi*3+2];
    const float nx = normals[mi*3+0], ny = normals[mi*3+1], nz = normals[mi*3+2];
    const float vx = px - qx, vy = py - qy, vz = pz - qz;
    float* ppfrow = (float*)&s_h[g][k][64];
    if (lane < KNB) {
      ppfrow[1] = angle3f(qnx,qny,qnz, vx,vy,vz);
      ppfrow[2] = angle3f(nx,ny,nz,    vx,vy,vz);
    } else {
      ppfrow[0] = __builtin_amdgcn_sqrtf(vx*vx + vy*vy + vz*vz);
      ppfrow[3] = angle3f(qnx,qny,qnz, nx,ny,nz);
    }
  }
  // ppf produced and consumed by the same wave; DS ops are in-order per wave.

  // ---- Layer 1: h1 = relu(ppf @ W1^T + b1) via MFMA -------------------------
  {
    BF8 a1[2];
    a1[0].u[0]=a1[0].u[1]=a1[0].u[2]=a1[0].u[3]=0;
    a1[1] = a1[0];
    if (lq == 0) {
#pragma unroll
      for (int rt = 0; rt < 2; ++rt) {
        const float4 pv = *(const float4*)&s_h[g][ln + 16*rt][64];
        a1[rt].us[0]=f2bf(pv.x); a1[rt].us[1]=f2bf(pv.y);
        a1[rt].us[2]=f2bf(pv.z); a1[rt].us[3]=f2bf(pv.w);
      }
    }
#pragma unroll
    for (int ct = 0; ct < 4; ++ct) {
      const bf16x8 bw = *(const bf16x8*)&wsu[WS_W1 + ct*512 + lane*8];
      const float  bv = b1[ln + 16*ct];
#pragma unroll
      for (int rt = 0; rt < 2; ++rt) {
        f32x4 c = {bv, bv, bv, bv};
        c = __builtin_amdgcn_mfma_f32_16x16x32_bf16(a1[rt].v, bw, c, 0, 0, 0);
#pragma unroll
        for (int r = 0; r < 4; ++r)   // writes cols 0..63 only; ppf pad intact
          s_h[g][lq*4 + r + 16*rt][ln + 16*ct] = f2bf(fmaxf(c[r], 0.f));
      }
    }
  }

  gather_issue(s_feats, nbr, pu, 8, lofs, bufB);   // chunk 1 in flight
  gather_acc(bufA, s0, s1, s2);                    // consume chunk 0

  // ---- Layer 2: h2 = relu(h1 @ W2^T + b2), in place -------------------------
  // (in-place safe: the wave's 4 A-frag ds_reads precede all its ds_writes)
  {
    bf16x8 wf[8];
#pragma unroll
    for (int fIdx = 0; fIdx < 8; ++fIdx)
      wf[fIdx] = *(const bf16x8*)&wsu[WS_W2 + fIdx*512 + lane*8];
    bf16x8 a2[4];
#pragma unroll
    for (int rt = 0; rt < 2; ++rt)
#pragma unroll
      for (int ks = 0; ks < 2; ++ks)
        a2[rt*2+ks] = *(const bf16x8*)&s_h[g][ln + 16*rt][lq*8 + ks*32];
#pragma unroll
    for (int ct = 0; ct < 4; ++ct) {
      const float bv = b2[ln + 16*ct];
#pragma unroll
      for (int rt = 0; rt < 2; ++rt) {
        f32x4 c = {bv, bv, bv, bv};
        c = __builtin_amdgcn_mfma_f32_16x16x32_bf16(a2[rt*2+0], wf[ct*2+0], c, 0, 0, 0);
        c = __builtin_amdgcn_mfma_f32_16x16x32_bf16(a2[rt*2+1], wf[ct*2+1], c, 0, 0, 0);
#pragma unroll
        for (int r = 0; r < 4; ++r)
          s_h[g][lq*4 + r + 16*rt][ln + 16*ct] = f2bf(fmaxf(c[r], 0.f));
      }
    }
  }

  gather_issue(s_feats, nbr, pu, 16, lofs, bufA);  // chunk 2 in flight
  gather_acc(bufB, s0, s1, s2);                    // consume chunk 1

  // ---- Layer 3 + fused mean over K -> s_modb (bf16, row = point) ------------
  {
    bf16x8 wf[8];
#pragma unroll
    for (int fIdx = 0; fIdx < 8; ++fIdx)
      wf[fIdx] = *(const bf16x8*)&wsu[WS_W3 + fIdx*512 + lane*8];
    bf16x8 a3[4];
#pragma unroll
    for (int rt = 0; rt < 2; ++rt)
#pragma unroll
      for (int ks = 0; ks < 2; ++ks)
        a3[rt*2+ks] = *(const bf16x8*)&s_h[g][ln + 16*rt][lq*8 + ks*32];
#pragma unroll
    for (int ct = 0; ct < 4; ++ct) {
      const float bv = b3[ln + 16*ct];
      f32x4 c0 = {bv, bv, bv, bv};
      c0 = __builtin_amdgcn_mfma_f32_16x16x32_bf16(a3[0], wf[ct*2+0], c0, 0, 0, 0);
      c0 = __builtin_amdgcn_mfma_f32_16x16x32_bf16(a3[1], wf[ct*2+1], c0, 0, 0, 0);
      f32x4 c1 = {bv, bv, bv, bv};
      c1 = __builtin_amdgcn_mfma_f32_16x16x32_bf16(a3[2], wf[ct*2+0], c1, 0, 0, 0);
      c1 = __builtin_amdgcn_mfma_f32_16x16x32_bf16(a3[3], wf[ct*2+1], c1, 0, 0, 0);
      float s = (c0[0]+c0[1]+c0[2]+c0[3]) + (c1[0]+c1[1]+c1[2]+c1[3]);
      s += __shfl_xor(s, 16);
      s += __shfl_xor(s, 32);
      if (lq == 0) s_modb[g][ln + 16*ct] = f2bf(s * (1.f/KNB));
    }
  }

  gather_issue(s_feats, nbr, pu, 24, lofs, bufB);  // chunk 3
  gather_acc(bufA, s0, s1, s2);                    // consume chunk 2
  gather_acc(bufB, s0, s1, s2);                    // consume chunk 3

  // s_aggb row n = g*3+t, col d = lane
  s_aggb[g*3+0][lane] = f2bf(s0 * (1.f/KNB));
  s_aggb[g*3+1][lane] = f2bf(s1 * (1.f/KNB));
  s_aggb[g*3+2][lane] = f2bf(s2 * (1.f/KNB));

  __syncthreads();   // s_modb/s_aggb cross-wave; also all s_h frag reads drained

  // ---- Gate via MFMA: rows = points (4 valid), cols = 192 outputs -----------
  {
    const bf16x8 am0 = *(const bf16x8*)&s_modb[ln][lq*8];
    const bf16x8 am1 = *(const bf16x8*)&s_modb[ln][lq*8 + 32];
#pragma unroll
    for (int t = 0; t < 3; ++t) {
      const int ot = g*3 + t;                       // this wave's 3 col-tiles
      const bf16x8 bg0 = *(const bf16x8*)&wsu[WS_WG + (ot*2+0)*512 + lane*8];
      const bf16x8 bg1 = *(const bf16x8*)&wsu[WS_WG + (ot*2+1)*512 + lane*8];
      const float  bv  = bg[ln + 16*ot];
      f32x4 c = {bv, bv, bv, bv};
      c = __builtin_amdgcn_mfma_f32_16x16x32_bf16(am0, bg0, c, 0, 0, 0);
      c = __builtin_amdgcn_mfma_f32_16x16x32_bf16(am1, bg1, c, 0, 0, 0);
      if (lq == 0) {
#pragma unroll
        for (int r = 0; r < 4; ++r)   // row r = point r
          s_gate[r][ln + 16*ot] = 1.f / (1.f + __expf(-c[r]));
      }
    }
  }

  // ---- Transform via MFMA: rows = outputs, cols = (point,t) -----------------
  {
    const bf16x8 ab0 = *(const bf16x8*)&s_aggb[ln][lq*8];        // B[n=(g,t)][k=d]
    const bf16x8 ab1 = *(const bf16x8*)&s_aggb[ln][lq*8 + 32];
    const int gi = ln / 3;            // valid for ln < 12
    const int tt = ln - gi*3;
#pragma unroll
    for (int t2 = 0; t2 < 3; ++t2) {
      const int ot = g*3 + t2;                      // this wave's 3 row-tiles
      const bf16x8 av0 = *(const bf16x8*)&wsu[WS_WV + (ot*2+0)*512 + lane*8];
      const bf16x8 av1 = *(const bf16x8*)&wsu[WS_WV + (ot*2+1)*512 + lane*8];
      f32x4 c = {0.f, 0.f, 0.f, 0.f};
      c = __builtin_amdgcn_mfma_f32_16x16x32_bf16(av0, ab0, c, 0, 0, 0);
      c = __builtin_amdgcn_mfma_f32_16x16x32_bf16(av1, ab1, c, 0, 0, 0);
      if (ln < 12) {
#pragma unroll
        for (int r = 0; r < 4; ++r) {
          const int o = 16*ot + lq*4 + r;
          s_out[gi*592 + o*3 + tt] = c[r] * s_gate[gi][o];
        }
      }
    }
  }
  __syncthreads();

  // ---- Coalesced float4 output write ----------------------------------------
  {
    float4* outv = (float4*)out;
    const float4* sov = (const float4*)s_out;
#pragma unroll
    for (int i = 0; i < 3; ++i) {
      const int idx = tid + 256*i;
      if (idx < 576) {
        const int gg  = idx / 144;
        const int off = idx - gg*144;
        outv[(size_t)blockIdx.x * 576 + idx] = sov[gg*148 + off];
      }
    }
  }
}

extern "C" void kernel_launch(void* const* d_in, const int* in_sizes, int n_in,
                              void* d_out, int out_size, void* d_ws, size_t ws_size,
                              hipStream_t stream) {
  const float* q_pts   = (const float*)d_in[0];
  const float* s_pts   = (const float*)d_in[1];
  const float* s_feats = (const float*)d_in[2];
  const int*   nbr     = (const int*)  d_in[3];
  const float* normals = (const float*)d_in[4];
  const float* W1 = (const float*)d_in[5];
  const float* b1 = (const float*)d_in[6];
  const float* W2 = (const float*)d_in[7];
  const float* b2 = (const float*)d_in[8];
  const float* W3 = (const float*)d_in[9];
  const float* b3 = (const float*)d_in[10];
  const float* Wg = (const float*)d_in[11];
  const float* bg = (const float*)d_in[12];
  const float* Wv = (const float*)d_in[13];
  float* out = (float*)d_out;
  unsigned short* ws = (unsigned short*)d_ws;

  hipLaunchKernelGGL(prep_weights, dim3(68), dim3(64), 0, stream,
                     W1, W2, W3, Wg, Wv, ws);
  hipLaunchKernelGGL(ppf_fused, dim3(NPTS / PPB), dim3(256), 0, stream,
                     q_pts, s_pts, s_feats, nbr, normals,
                     b1, b2, b3, bg, ws, out);
}